// Round 4
// baseline (580.013 us; speedup 1.0000x reference)
//
#include <hip/hip_runtime.h>
#include <hip/hip_fp16.h>
#include <hip/hip_cooperative_groups.h>

namespace cg = cooperative_groups;

#define LRELU(v) ((v) > 0.0f ? (v) : 0.2f * (v))

constexpr int F_IN = 128;
constexpr int NH1  = 6;
constexpr int D1   = 192;   // NH1 * 32

typedef _Float16 half8 __attribute__((ext_vector_type(8)));
typedef float floatx4 __attribute__((ext_vector_type(4)));

__device__ __forceinline__ void wave_lds_fence() {
  __builtin_amdgcn_wave_barrier();
  asm volatile("s_waitcnt lgkmcnt(0)" ::: "memory");
  __builtin_amdgcn_wave_barrier();
}

// ---------------- cooperative: prep (fp16 casts) + CSR build ----------------
// phase0: x->fp16, W1 -> fp16 transposed [192][128], zero cnt
// phase1: histogram  phase2: 3-step scan  phase3: scatter
__global__ __launch_bounds__(256, 2) void k_csr(
    const float* __restrict__ x, const float* __restrict__ W1,
    const int* __restrict__ src, const int* __restrict__ dst,
    __half* __restrict__ x_h, __half* __restrict__ w1t,
    int* __restrict__ cnt, int* __restrict__ offs, int* __restrict__ cursor,
    int* __restrict__ bsum, int* __restrict__ boff,
    int* __restrict__ ssort, int N, int E) {
  cg::grid_group grid = cg::this_grid();
  __shared__ int wt[4];
  const int t = threadIdx.x;
  const int tid = blockIdx.x * 256 + t;
  const int nthr = gridDim.x * 256;
  const int NB = (N + 255) >> 8;

  // ---- phase 0 ----
  const int totx4 = N * F_IN / 4;
  for (int i = tid; i < totx4; i += nthr) {
    float4 v = ((const float4*)x)[i];
    ushort4 h;
    h.x = __half_as_ushort(__float2half(v.x));
    h.y = __half_as_ushort(__float2half(v.y));
    h.z = __half_as_ushort(__float2half(v.z));
    h.w = __half_as_ushort(__float2half(v.w));
    *(ushort4*)(x_h + 4 * (size_t)i) = h;
  }
  for (int i = tid; i < F_IN * D1; i += nthr) {
    int k = i / D1, n = i - k * D1;        // coalesced read of W1[k][n]
    w1t[(size_t)n * F_IN + k] = __float2half(W1[i]);
  }
  for (int i = tid; i < N; i += nthr) cnt[i] = 0;
  grid.sync();

  // ---- phase 1: histogram ----
  for (int e = tid; e < E; e += nthr) atomicAdd(&cnt[dst[e]], 1);
  grid.sync();

  // ---- phase 2a: per-chunk exclusive scan ----
  if ((int)blockIdx.x < NB) {
    int lane = t & 63, w = t >> 6;
    int idx = blockIdx.x * 256 + t;
    int v = (idx < N) ? cnt[idx] : 0;
    int incl = v;
#pragma unroll
    for (int d = 1; d < 64; d <<= 1) {
      int u = __shfl_up(incl, d);
      if (lane >= d) incl += u;
    }
    if (lane == 63) wt[w] = incl;
    __syncthreads();
    int woff = 0;
    for (int i = 0; i < w; ++i) woff += wt[i];
    if (idx < N) offs[idx] = woff + incl - v;
    if (t == 255) bsum[blockIdx.x] = woff + incl;
  }
  grid.sync();

  // ---- phase 2b: block 0 scans the NB block sums (NB <= 256) ----
  if (blockIdx.x == 0) {
    int lane = t & 63, w = t >> 6;
    int v = (t < NB) ? bsum[t] : 0;
    int incl = v;
#pragma unroll
    for (int d = 1; d < 64; d <<= 1) {
      int u = __shfl_up(incl, d);
      if (lane >= d) incl += u;
    }
    __syncthreads();   // wt reuse hazard from 2a
    if (lane == 63) wt[w] = incl;
    __syncthreads();
    int woff = 0;
    for (int i = 0; i < w; ++i) woff += wt[i];
    if (t < NB) boff[t] = woff + incl - v;
  }
  grid.sync();

  // ---- phase 2c: finalize offs / cursor ----
  if ((int)blockIdx.x < NB) {
    int idx = blockIdx.x * 256 + t;
    if (idx < N) {
      int v = offs[idx] + boff[blockIdx.x];
      offs[idx] = v;
      cursor[idx] = v;
    }
  }
  if (tid == 0) offs[N] = boff[NB - 1] + bsum[NB - 1];
  grid.sync();

  // ---- phase 3: scatter srcs sorted by dst ----
  for (int e = tid; e < E; e += nthr) {
    int d = dst[e];
    int p = atomicAdd(&cursor[d], 1);
    ssort[p] = src[e];
  }
}

// ---------------- GEMM1 via MFMA: h1h[N,192] = x_h[N,128] @ W1[128,192] ----------------
// one wave per 16 rows; 12 column-frags of 16; K in 4 steps of 32.
// A frag: lane holds x_h[m0+(lane&15)][kc + (lane>>4)*8 + j]  (16B contiguous)
// B frag: lane holds W1t[n0+(lane&15)][kc + (lane>>4)*8 + j]  (16B contiguous)
// C frag: col = lane&15, row = (lane>>4)*4 + reg
__global__ __launch_bounds__(256) void k_gemm1(const __half* __restrict__ x_h,
                                               const __half* __restrict__ w1t,
                                               __half* __restrict__ h1h, int N) {
  int wv = blockIdx.x * 4 + (threadIdx.x >> 6);
  int m0 = wv * 16;
  if (m0 >= N) return;
  int lane = threadIdx.x & 63;
  int ln15 = lane & 15, q = lane >> 4;

  floatx4 acc[12];
#pragma unroll
  for (int f = 0; f < 12; ++f) acc[f] = (floatx4){0.f, 0.f, 0.f, 0.f};

  const __half* arow = x_h + (size_t)(m0 + ln15) * F_IN + q * 8;
#pragma unroll
  for (int kc = 0; kc < F_IN; kc += 32) {
    half8 a = *(const half8*)(arow + kc);
#pragma unroll
    for (int f = 0; f < 12; ++f) {
      const __half* bp = w1t + (size_t)(16 * f + ln15) * F_IN + kc + q * 8;
      half8 b = *(const half8*)bp;
      acc[f] = __builtin_amdgcn_mfma_f32_16x16x32_f16(a, b, acc[f], 0, 0, 0);
    }
  }
#pragma unroll
  for (int f = 0; f < 12; ++f) {
#pragma unroll
    for (int r = 0; r < 4; ++r) {
      h1h[(size_t)(m0 + q * 4 + r) * D1 + 16 * f + ln15] = __float2half(acc[f][r]);
    }
  }
}

// ---------------- attention logits layer 1 (fp16 h1 input) ----------------
__global__ void k_al1(const __half* __restrict__ h1h, const float* __restrict__ a1s,
                      const float* __restrict__ a1d, float* __restrict__ als,
                      float* __restrict__ ald, int N) {
  int idx = blockIdx.x * blockDim.x + threadIdx.x;
  if (idx >= N * NH1) return;
  int n = idx / NH1, h = idx - n * NH1;
  const __half2* hp = (const __half2*)(h1h + (size_t)n * D1 + h * 32);
  const float2* as = (const float2*)(a1s + h * 32);
  const float2* ad = (const float2*)(a1d + h * 32);
  float ss = 0.f, sd = 0.f;
#pragma unroll
  for (int c = 0; c < 16; ++c) {
    float2 v = __half22float2(hp[c]);
    float2 vs = as[c], vd = ad[c];
    ss += v.x * vs.x + v.y * vs.y;
    sd += v.x * vd.x + v.y * vd.y;
  }
  als[idx] = ss;
  ald[idx] = sd;
}

// ---------------- layer-1 aggregation + fused layer-2 node transform ----------------
__global__ __launch_bounds__(256) void k_agg1(
    const __half* __restrict__ h1h, const float* __restrict__ als, const float* __restrict__ ald,
    const int* __restrict__ offs, const int* __restrict__ srcs,
    const float* __restrict__ b1, const float* __restrict__ W2,
    const float* __restrict__ a2s, const float* __restrict__ a2d,
    float* __restrict__ h2, float* __restrict__ al2s, float* __restrict__ al2d, int N) {
  __shared__ float wbuf[4][64][9];
  int wid = threadIdx.x >> 6, lane = threadIdx.x & 63;
  int d = blockIdx.x * 4 + wid;
  if (d >= N) return;
  int off = offs[d], cnt = offs[d + 1] - off;
  int tot = cnt + 1;

  float aldh[6];
  {
    const float* ap = ald + (size_t)d * 6;
    float2 q0 = *(const float2*)ap, q1 = *(const float2*)(ap + 2), q2 = *(const float2*)(ap + 4);
    aldh[0] = q0.x; aldh[1] = q0.y; aldh[2] = q1.x;
    aldh[3] = q1.y; aldh[4] = q2.x; aldh[5] = q2.y;
  }

  float dh[6] = {0.f, 0.f, 0.f, 0.f, 0.f, 0.f};
  int nchunk = (tot + 63) >> 6;

  float a0 = 0.f, a1 = 0.f, a2 = 0.f;
  const int hw = lane >> 4;
  const int hh = 4 + (lane >> 5);

  auto body = [&](int j) {
    float w_a = wbuf[wid][j][hw];
    float w_b = wbuf[wid][j][hh];
    int s = __float_as_int(wbuf[wid][j][6]);
    const __half* hp = h1h + (size_t)s * D1;
    float2 v = __half22float2(*(const __half2*)(hp + 2 * lane));
    float vh = __half2float(hp[128 + lane]);
    a0 = fmaf(w_a, v.x, a0);
    a1 = fmaf(w_a, v.y, a1);
    a2 = fmaf(w_b, vh, a2);
  };
  auto jloop = [&](int jmax) {
    int j = 0;
    for (; j + 3 < jmax; j += 4) { body(j); body(j + 1); body(j + 2); body(j + 3); }
    for (; j < jmax; ++j) body(j);
  };

  if (nchunk == 1) {
    float wreg[6];
    int sreg = 0;
    if (lane < tot) {
      int s = (lane == cnt) ? d : srcs[off + lane];
      sreg = s;
      const float* ap = als + (size_t)s * 6;
      float2 p0 = *(const float2*)ap, p1 = *(const float2*)(ap + 2), p2 = *(const float2*)(ap + 4);
      float ev[6] = {p0.x, p0.y, p1.x, p1.y, p2.x, p2.y};
#pragma unroll
      for (int h = 0; h < 6; ++h) {
        float e = ev[h] + aldh[h];
        e = LRELU(e);
        wreg[h] = __expf(e);
        dh[h] = wreg[h];
      }
    }
#pragma unroll
    for (int h = 0; h < 6; ++h) {
#pragma unroll
      for (int m = 32; m; m >>= 1) dh[h] += __shfl_xor(dh[h], m);
      dh[h] = 1.0f / dh[h];
    }
    if (lane < tot) {
#pragma unroll
      for (int h = 0; h < 6; ++h) wbuf[wid][lane][h] = wreg[h] * dh[h];
      wbuf[wid][lane][6] = __int_as_float(sreg);
    }
    wave_lds_fence();
    jloop(tot);
  } else {
    for (int c = 0; c < nchunk; ++c) {
      int i = c * 64 + lane;
      if (i < tot) {
        int s = (i == cnt) ? d : srcs[off + i];
        const float* ap = als + (size_t)s * 6;
        float2 p0 = *(const float2*)ap, p1 = *(const float2*)(ap + 2), p2 = *(const float2*)(ap + 4);
        float ev[6] = {p0.x, p0.y, p1.x, p1.y, p2.x, p2.y};
#pragma unroll
        for (int h = 0; h < 6; ++h) {
          float e = ev[h] + aldh[h];
          e = LRELU(e);
          dh[h] += __expf(e);
        }
      }
    }
#pragma unroll
    for (int h = 0; h < 6; ++h) {
#pragma unroll
      for (int m = 32; m; m >>= 1) dh[h] += __shfl_xor(dh[h], m);
      dh[h] = 1.0f / dh[h];
    }
    for (int c = 0; c < nchunk; ++c) {
      int i = c * 64 + lane;
      if (i < tot) {
        int s = (i == cnt) ? d : srcs[off + i];
        const float* ap = als + (size_t)s * 6;
        float2 p0 = *(const float2*)ap, p1 = *(const float2*)(ap + 2), p2 = *(const float2*)(ap + 4);
        float ev[6] = {p0.x, p0.y, p1.x, p1.y, p2.x, p2.y};
#pragma unroll
        for (int h = 0; h < 6; ++h) {
          float e = ev[h] + aldh[h];
          e = LRELU(e);
          wbuf[wid][lane][h] = __expf(e) * dh[h];
        }
        wbuf[wid][lane][6] = __int_as_float(s);
      }
      wave_lds_fence();
      int jmax = tot - c * 64;
      if (jmax > 64) jmax = 64;
      jloop(jmax);
      wave_lds_fence();
    }
  }

  float2 bv = *(const float2*)(b1 + 2 * lane);
  float v0 = fmaxf(a0 + bv.x, 0.f);
  float v1 = fmaxf(a1 + bv.y, 0.f);
  float v2 = fmaxf(a2 + b1[128 + lane], 0.f);
  float4 ww = *(const float4*)(W2 + 4 * lane);
  float2 wh = *(const float2*)(W2 + (128 + lane) * 2);
  float s0 = v0 * ww.x + v1 * ww.z + v2 * wh.x;
  float s1 = v0 * ww.y + v1 * ww.w + v2 * wh.y;
#pragma unroll
  for (int m = 32; m; m >>= 1) {
    s0 += __shfl_xor(s0, m);
    s1 += __shfl_xor(s1, m);
  }
  if (lane == 0) {
    h2[d * 2] = s0;
    h2[d * 2 + 1] = s1;
    al2s[d] = s0 * a2s[0] + s1 * a2s[1];
    al2d[d] = s0 * a2d[0] + s1 * a2d[1];
  }
}

// ---------------- layer-2 aggregation + bias + log_softmax ----------------
__global__ __launch_bounds__(256) void k_agg2(
    const float* __restrict__ h2, const float* __restrict__ al2s,
    const float* __restrict__ al2d, const int* __restrict__ offs,
    const int* __restrict__ srcs, const float* __restrict__ b2,
    float* __restrict__ out, int N) {
  int tid = blockIdx.x * 256 + threadIdx.x;
  int g = tid >> 3, r = tid & 7;
  if (g >= N) return;
  int off = offs[g], cnt = offs[g + 1] - off;
  int tot = cnt + 1;
  float ad = al2d[g];
  float den = 0.f, o0 = 0.f, o1 = 0.f;
  for (int i = r; i < tot; i += 8) {
    int s = (i == cnt) ? g : srcs[off + i];
    float e = al2s[s] + ad;
    e = LRELU(e);
    float a = __expf(e);
    float2 hv = *(const float2*)(h2 + (size_t)s * 2);
    den += a;
    o0 = fmaf(a, hv.x, o0);
    o1 = fmaf(a, hv.y, o1);
  }
#pragma unroll
  for (int m = 4; m; m >>= 1) {
    den += __shfl_xor(den, m);
    o0 += __shfl_xor(o0, m);
    o1 += __shfl_xor(o1, m);
  }
  if (r == 0) {
    float inv = 1.0f / den;
    o0 = o0 * inv + b2[0];
    o1 = o1 * inv + b2[1];
    float mm = fmaxf(o0, o1);
    float l = mm + logf(__expf(o0 - mm) + __expf(o1 - mm));
    *(float2*)(out + (size_t)g * 2) = make_float2(o0 - l, o1 - l);
  }
}

extern "C" void kernel_launch(void* const* d_in, const int* in_sizes, int n_in,
                              void* d_out, int out_size, void* d_ws, size_t ws_size,
                              hipStream_t stream) {
  const float* x   = (const float*)d_in[0];
  const int*   ei  = (const int*)d_in[1];
  const float* W1  = (const float*)d_in[2];
  const float* a1s = (const float*)d_in[3];
  const float* a1d = (const float*)d_in[4];
  const float* b1  = (const float*)d_in[5];
  const float* W2  = (const float*)d_in[6];
  const float* a2s = (const float*)d_in[7];
  const float* a2d = (const float*)d_in[8];
  const float* b2  = (const float*)d_in[9];
  float* out = (float*)d_out;

  const int N = in_sizes[0] / F_IN;   // 50000
  const int E = in_sizes[1] / 2;      // 800000
  const int* srcp = ei;
  const int* dstp = ei + E;

  char* w = (char*)d_ws;
  auto alloc = [&](size_t bytes) {
    char* p = w;
    w += (bytes + 255) & ~(size_t)255;
    return p;
  };
  __half* h1h   = (__half*)alloc((size_t)N * D1 * 2);
  __half* x_h   = (__half*)alloc((size_t)N * F_IN * 2);
  __half* w1t   = (__half*)alloc((size_t)F_IN * D1 * 2);
  float* als    = (float*)alloc((size_t)N * NH1 * 4);
  float* ald    = (float*)alloc((size_t)N * NH1 * 4);
  float* h2     = (float*)alloc((size_t)N * 2 * 4);
  float* al2s   = (float*)alloc((size_t)N * 4);
  float* al2d   = (float*)alloc((size_t)N * 4);
  int*   cnt    = (int*)alloc((size_t)N * 4);
  int*   offs   = (int*)alloc((size_t)(N + 1) * 4);
  int*   cursor = (int*)alloc((size_t)N * 4);
  int*   bsum   = (int*)alloc(1024);
  int*   boff   = (int*)alloc(1024);
  int*   ssort  = (int*)alloc((size_t)E * 4);

  int Nv = N, Ev = E;
  void* args[] = {
    (void*)&x, (void*)&W1, (void*)&srcp, (void*)&dstp,
    (void*)&x_h, (void*)&w1t,
    (void*)&cnt, (void*)&offs, (void*)&cursor,
    (void*)&bsum, (void*)&boff, (void*)&ssort,
    (void*)&Nv, (void*)&Ev
  };
  hipLaunchCooperativeKernel((const void*)k_csr, dim3(512), dim3(256), args, 0, stream);

  int nwave = (N + 15) / 16;
  k_gemm1<<<(nwave + 3) / 4, 256, 0, stream>>>(x_h, w1t, h1h, N);
  k_al1<<<(N * NH1 + 255) / 256, 256, 0, stream>>>(h1h, a1s, a1d, als, ald, N);

  k_agg1<<<(N + 3) / 4, 256, 0, stream>>>(h1h, als, ald, offs, ssort, b1, W2,
                                          a2s, a2d, h2, al2s, al2d, N);
  k_agg2<<<(N * 8 + 255) / 256, 256, 0, stream>>>(h2, al2s, al2d, offs, ssort, b2, out, N);
}

// Round 5
// 278.037 us; speedup vs baseline: 2.0861x; 2.0861x over previous
//
#include <hip/hip_runtime.h>
#include <hip/hip_fp16.h>

#define LRELU(v) ((v) > 0.0f ? (v) : 0.2f * (v))

constexpr int F_IN = 128;
constexpr int NH1  = 6;
constexpr int D1   = 192;   // NH1 * 32

typedef _Float16 half8 __attribute__((ext_vector_type(8)));
typedef float floatx4 __attribute__((ext_vector_type(4)));

__device__ __forceinline__ void wave_lds_fence() {
  __builtin_amdgcn_wave_barrier();
  asm volatile("s_waitcnt lgkmcnt(0)" ::: "memory");
  __builtin_amdgcn_wave_barrier();
}

// ---------------- prep: W1 -> fp16 transposed [192][128]; zero cnt ----------------
__global__ __launch_bounds__(256) void k_prep(const float* __restrict__ W1,
                                              __half* __restrict__ w1t,
                                              int* __restrict__ cnt, int N) {
  int tid = blockIdx.x * 256 + threadIdx.x;
  int nthr = gridDim.x * 256;
  for (int i = tid; i < F_IN * D1; i += nthr) {
    int k = i / D1, n = i - k * D1;   // coalesced read of W1[k][n]
    w1t[(size_t)n * F_IN + k] = __float2half(W1[i]);
  }
  for (int i = tid; i < N; i += nthr) cnt[i] = 0;
}

// ---------------- GEMM1 via MFMA + fused attention-logit epilogue ----------------
// h1h[N,192] = fp16( fp32 x[N,128] @ fp16 W1t ) ; als/ald[N,6] from fp32 C-frags.
// A frag: lane holds x[m0+(lane&15)][kc + q*8 + j]   (fp32->fp16 in-register)
// B frag: lane holds W1t[16f+(lane&15)][kc + q*8 + j] (16B contiguous)
// C frag: col = 16f + (lane&15), row = q*4 + reg ; head of frag f = f>>1
__global__ __launch_bounds__(256) void k_gemm1(const float* __restrict__ x,
                                               const __half* __restrict__ w1t,
                                               const float* __restrict__ a1s,
                                               const float* __restrict__ a1d,
                                               __half* __restrict__ h1h,
                                               float* __restrict__ als,
                                               float* __restrict__ ald, int N) {
  int wv = blockIdx.x * 4 + (threadIdx.x >> 6);
  int m0 = wv * 16;
  if (m0 >= N) return;
  int lane = threadIdx.x & 63;
  int ln15 = lane & 15, q = lane >> 4;

  // attention vector elements this lane's columns touch: channel (f&1)*16+ln15 of head f>>1
  float avs[12], avd[12];
#pragma unroll
  for (int f = 0; f < 12; ++f) {
    int idx = (f >> 1) * 32 + (f & 1) * 16 + ln15;
    avs[f] = a1s[idx];
    avd[f] = a1d[idx];
  }

  floatx4 acc[12];
#pragma unroll
  for (int f = 0; f < 12; ++f) acc[f] = (floatx4){0.f, 0.f, 0.f, 0.f};

  int arowi = m0 + ln15;
  if (arowi >= N) arowi = N - 1;              // clamp (harmless dup row; writes guarded)
  const float* arow = x + (size_t)arowi * F_IN + q * 8;
#pragma unroll
  for (int kc = 0; kc < F_IN; kc += 32) {
    float4 u0 = *(const float4*)(arow + kc);
    float4 u1 = *(const float4*)(arow + kc + 4);
    half8 a;
    a[0] = (_Float16)u0.x; a[1] = (_Float16)u0.y; a[2] = (_Float16)u0.z; a[3] = (_Float16)u0.w;
    a[4] = (_Float16)u1.x; a[5] = (_Float16)u1.y; a[6] = (_Float16)u1.z; a[7] = (_Float16)u1.w;
#pragma unroll
    for (int f = 0; f < 12; ++f) {
      half8 b = *(const half8*)(w1t + (size_t)(16 * f + ln15) * F_IN + kc + q * 8);
      acc[f] = __builtin_amdgcn_mfma_f32_16x16x32_f16(a, b, acc[f], 0, 0, 0);
    }
  }

  // write h1h (fp16)
#pragma unroll
  for (int f = 0; f < 12; ++f) {
#pragma unroll
    for (int r = 0; r < 4; ++r) {
      int n = m0 + q * 4 + r;
      if (n < N) h1h[(size_t)n * D1 + 16 * f + ln15] = __float2half(acc[f][r]);
    }
  }

  // fused al1: per row r, 6-head dot + 16-lane butterfly reduce
#pragma unroll
  for (int r = 0; r < 4; ++r) {
    float ps[6] = {0.f, 0.f, 0.f, 0.f, 0.f, 0.f};
    float pd[6] = {0.f, 0.f, 0.f, 0.f, 0.f, 0.f};
#pragma unroll
    for (int f = 0; f < 12; ++f) {
      ps[f >> 1] = fmaf(acc[f][r], avs[f], ps[f >> 1]);
      pd[f >> 1] = fmaf(acc[f][r], avd[f], pd[f >> 1]);
    }
#pragma unroll
    for (int h = 0; h < 6; ++h) {
#pragma unroll
      for (int m = 8; m; m >>= 1) {
        ps[h] += __shfl_xor(ps[h], m);
        pd[h] += __shfl_xor(pd[h], m);
      }
    }
    float os = 0.f, od = 0.f;
#pragma unroll
    for (int h = 0; h < 6; ++h)
      if (ln15 == h) { os = ps[h]; od = pd[h]; }
    int n = m0 + q * 4 + r;
    if (ln15 < 6 && n < N) {
      als[(size_t)n * 6 + ln15] = os;
      ald[(size_t)n * 6 + ln15] = od;
    }
  }
}

// ---------------- CSR build ----------------
__global__ void k_hist(const int* __restrict__ dst, int* __restrict__ cnt, int E) {
  int e = blockIdx.x * 256 + threadIdx.x;
  if (e < E) atomicAdd(&cnt[dst[e]], 1);
}

__global__ void k_scan1(const int* __restrict__ cnt, int* __restrict__ offs,
                        int* __restrict__ bsum, int N) {
  int t = threadIdx.x;
  int idx = blockIdx.x * 256 + t;
  int lane = t & 63, w = t >> 6;
  int v = (idx < N) ? cnt[idx] : 0;
  int incl = v;
#pragma unroll
  for (int d = 1; d < 64; d <<= 1) {
    int u = __shfl_up(incl, d);
    if (lane >= d) incl += u;
  }
  __shared__ int wt[4];
  if (lane == 63) wt[w] = incl;
  __syncthreads();
  int woff = 0;
  for (int i = 0; i < w; ++i) woff += wt[i];
  if (idx < N) offs[idx] = woff + incl - v;
  if (t == 255) bsum[blockIdx.x] = woff + incl;
}

__global__ void k_scan2(int* __restrict__ bsum, int* __restrict__ boff, int NB) {
  int t = threadIdx.x;
  int lane = t & 63, w = t >> 6;
  int v = (t < NB) ? bsum[t] : 0;
  int incl = v;
#pragma unroll
  for (int d = 1; d < 64; d <<= 1) {
    int u = __shfl_up(incl, d);
    if (lane >= d) incl += u;
  }
  __shared__ int wt[4];
  if (lane == 63) wt[w] = incl;
  __syncthreads();
  int woff = 0;
  for (int i = 0; i < w; ++i) woff += wt[i];
  if (t < NB) boff[t] = woff + incl - v;
}

__global__ void k_scan3(int* __restrict__ offs, int* __restrict__ cursor,
                        const int* __restrict__ boff, const int* __restrict__ bsum,
                        int N, int NB) {
  int idx = blockIdx.x * 256 + threadIdx.x;
  if (idx < N) {
    int v = offs[idx] + boff[blockIdx.x];
    offs[idx] = v;
    cursor[idx] = v;
  }
  if (idx == 0) offs[N] = boff[NB - 1] + bsum[NB - 1];
}

__global__ void k_scatter(const int* __restrict__ src, const int* __restrict__ dst,
                          int* __restrict__ cursor, int* __restrict__ ss, int E) {
  int e = blockIdx.x * 256 + threadIdx.x;
  if (e < E) {
    int d = dst[e];
    int p = atomicAdd(&cursor[d], 1);
    ss[p] = src[e];
  }
}

// ---------------- layer-1 aggregation + fused layer-2 node transform ----------------
__global__ __launch_bounds__(256) void k_agg1(
    const __half* __restrict__ h1h, const float* __restrict__ als, const float* __restrict__ ald,
    const int* __restrict__ offs, const int* __restrict__ srcs,
    const float* __restrict__ b1, const float* __restrict__ W2,
    const float* __restrict__ a2s, const float* __restrict__ a2d,
    float* __restrict__ h2, float* __restrict__ al2s, float* __restrict__ al2d, int N) {
  __shared__ float wbuf[4][64][9];
  int wid = threadIdx.x >> 6, lane = threadIdx.x & 63;
  int d = blockIdx.x * 4 + wid;
  if (d >= N) return;
  int off = offs[d], cnt = offs[d + 1] - off;
  int tot = cnt + 1;

  float aldh[6];
  {
    const float* ap = ald + (size_t)d * 6;
    float2 q0 = *(const float2*)ap, q1 = *(const float2*)(ap + 2), q2 = *(const float2*)(ap + 4);
    aldh[0] = q0.x; aldh[1] = q0.y; aldh[2] = q1.x;
    aldh[3] = q1.y; aldh[4] = q2.x; aldh[5] = q2.y;
  }

  float dh[6] = {0.f, 0.f, 0.f, 0.f, 0.f, 0.f};
  int nchunk = (tot + 63) >> 6;

  float a0 = 0.f, a1 = 0.f, a2 = 0.f;
  const int hw = lane >> 4;
  const int hh = 4 + (lane >> 5);

  auto body = [&](int j) {
    float w_a = wbuf[wid][j][hw];
    float w_b = wbuf[wid][j][hh];
    int s = __float_as_int(wbuf[wid][j][6]);
    const __half* hp = h1h + (size_t)s * D1;
    float2 v = __half22float2(*(const __half2*)(hp + 2 * lane));
    float vh = __half2float(hp[128 + lane]);
    a0 = fmaf(w_a, v.x, a0);
    a1 = fmaf(w_a, v.y, a1);
    a2 = fmaf(w_b, vh, a2);
  };
  auto jloop = [&](int jmax) {
    int j = 0;
    for (; j + 3 < jmax; j += 4) { body(j); body(j + 1); body(j + 2); body(j + 3); }
    for (; j < jmax; ++j) body(j);
  };

  if (nchunk == 1) {
    float wreg[6];
    int sreg = 0;
    if (lane < tot) {
      int s = (lane == cnt) ? d : srcs[off + lane];
      sreg = s;
      const float* ap = als + (size_t)s * 6;
      float2 p0 = *(const float2*)ap, p1 = *(const float2*)(ap + 2), p2 = *(const float2*)(ap + 4);
      float ev[6] = {p0.x, p0.y, p1.x, p1.y, p2.x, p2.y};
#pragma unroll
      for (int h = 0; h < 6; ++h) {
        float e = ev[h] + aldh[h];
        e = LRELU(e);
        wreg[h] = __expf(e);
        dh[h] = wreg[h];
      }
    }
#pragma unroll
    for (int h = 0; h < 6; ++h) {
#pragma unroll
      for (int m = 32; m; m >>= 1) dh[h] += __shfl_xor(dh[h], m);
      dh[h] = 1.0f / dh[h];
    }
    if (lane < tot) {
#pragma unroll
      for (int h = 0; h < 6; ++h) wbuf[wid][lane][h] = wreg[h] * dh[h];
      wbuf[wid][lane][6] = __int_as_float(sreg);
    }
    wave_lds_fence();
    jloop(tot);
  } else {
    for (int c = 0; c < nchunk; ++c) {
      int i = c * 64 + lane;
      if (i < tot) {
        int s = (i == cnt) ? d : srcs[off + i];
        const float* ap = als + (size_t)s * 6;
        float2 p0 = *(const float2*)ap, p1 = *(const float2*)(ap + 2), p2 = *(const float2*)(ap + 4);
        float ev[6] = {p0.x, p0.y, p1.x, p1.y, p2.x, p2.y};
#pragma unroll
        for (int h = 0; h < 6; ++h) {
          float e = ev[h] + aldh[h];
          e = LRELU(e);
          dh[h] += __expf(e);
        }
      }
    }
#pragma unroll
    for (int h = 0; h < 6; ++h) {
#pragma unroll
      for (int m = 32; m; m >>= 1) dh[h] += __shfl_xor(dh[h], m);
      dh[h] = 1.0f / dh[h];
    }
    for (int c = 0; c < nchunk; ++c) {
      int i = c * 64 + lane;
      if (i < tot) {
        int s = (i == cnt) ? d : srcs[off + i];
        const float* ap = als + (size_t)s * 6;
        float2 p0 = *(const float2*)ap, p1 = *(const float2*)(ap + 2), p2 = *(const float2*)(ap + 4);
        float ev[6] = {p0.x, p0.y, p1.x, p1.y, p2.x, p2.y};
#pragma unroll
        for (int h = 0; h < 6; ++h) {
          float e = ev[h] + aldh[h];
          e = LRELU(e);
          wbuf[wid][lane][h] = __expf(e) * dh[h];
        }
        wbuf[wid][lane][6] = __int_as_float(s);
      }
      wave_lds_fence();
      int jmax = tot - c * 64;
      if (jmax > 64) jmax = 64;
      jloop(jmax);
      wave_lds_fence();
    }
  }

  float2 bv = *(const float2*)(b1 + 2 * lane);
  float v0 = fmaxf(a0 + bv.x, 0.f);
  float v1 = fmaxf(a1 + bv.y, 0.f);
  float v2 = fmaxf(a2 + b1[128 + lane], 0.f);
  float4 ww = *(const float4*)(W2 + 4 * lane);
  float2 wh = *(const float2*)(W2 + (128 + lane) * 2);
  float s0 = v0 * ww.x + v1 * ww.z + v2 * wh.x;
  float s1 = v0 * ww.y + v1 * ww.w + v2 * wh.y;
#pragma unroll
  for (int m = 32; m; m >>= 1) {
    s0 += __shfl_xor(s0, m);
    s1 += __shfl_xor(s1, m);
  }
  if (lane == 0) {
    h2[d * 2] = s0;
    h2[d * 2 + 1] = s1;
    al2s[d] = s0 * a2s[0] + s1 * a2s[1];
    al2d[d] = s0 * a2d[0] + s1 * a2d[1];
  }
}

// ---------------- layer-2 aggregation + bias + log_softmax ----------------
__global__ __launch_bounds__(256) void k_agg2(
    const float* __restrict__ h2, const float* __restrict__ al2s,
    const float* __restrict__ al2d, const int* __restrict__ offs,
    const int* __restrict__ srcs, const float* __restrict__ b2,
    float* __restrict__ out, int N) {
  int tid = blockIdx.x * 256 + threadIdx.x;
  int g = tid >> 3, r = tid & 7;
  if (g >= N) return;
  int off = offs[g], cnt = offs[g + 1] - off;
  int tot = cnt + 1;
  float ad = al2d[g];
  float den = 0.f, o0 = 0.f, o1 = 0.f;
  for (int i = r; i < tot; i += 8) {
    int s = (i == cnt) ? g : srcs[off + i];
    float e = al2s[s] + ad;
    e = LRELU(e);
    float a = __expf(e);
    float2 hv = *(const float2*)(h2 + (size_t)s * 2);
    den += a;
    o0 = fmaf(a, hv.x, o0);
    o1 = fmaf(a, hv.y, o1);
  }
#pragma unroll
  for (int m = 4; m; m >>= 1) {
    den += __shfl_xor(den, m);
    o0 += __shfl_xor(o0, m);
    o1 += __shfl_xor(o1, m);
  }
  if (r == 0) {
    float inv = 1.0f / den;
    o0 = o0 * inv + b2[0];
    o1 = o1 * inv + b2[1];
    float mm = fmaxf(o0, o1);
    float l = mm + logf(__expf(o0 - mm) + __expf(o1 - mm));
    *(float2*)(out + (size_t)g * 2) = make_float2(o0 - l, o1 - l);
  }
}

extern "C" void kernel_launch(void* const* d_in, const int* in_sizes, int n_in,
                              void* d_out, int out_size, void* d_ws, size_t ws_size,
                              hipStream_t stream) {
  const float* x   = (const float*)d_in[0];
  const int*   ei  = (const int*)d_in[1];
  const float* W1  = (const float*)d_in[2];
  const float* a1s = (const float*)d_in[3];
  const float* a1d = (const float*)d_in[4];
  const float* b1  = (const float*)d_in[5];
  const float* W2  = (const float*)d_in[6];
  const float* a2s = (const float*)d_in[7];
  const float* a2d = (const float*)d_in[8];
  const float* b2  = (const float*)d_in[9];
  float* out = (float*)d_out;

  const int N = in_sizes[0] / F_IN;   // 50000
  const int E = in_sizes[1] / 2;      // 800000
  const int* srcp = ei;
  const int* dstp = ei + E;

  char* w = (char*)d_ws;
  auto alloc = [&](size_t bytes) {
    char* p = w;
    w += (bytes + 255) & ~(size_t)255;
    return p;
  };
  __half* h1h   = (__half*)alloc((size_t)N * D1 * 2);
  __half* w1t   = (__half*)alloc((size_t)F_IN * D1 * 2);
  float* als    = (float*)alloc((size_t)N * NH1 * 4);
  float* ald    = (float*)alloc((size_t)N * NH1 * 4);
  float* h2     = (float*)alloc((size_t)N * 2 * 4);
  float* al2s   = (float*)alloc((size_t)N * 4);
  float* al2d   = (float*)alloc((size_t)N * 4);
  int*   cnt    = (int*)alloc((size_t)N * 4);
  int*   offs   = (int*)alloc((size_t)(N + 1) * 4);
  int*   cursor = (int*)alloc((size_t)N * 4);
  int*   bsum   = (int*)alloc(1024);
  int*   boff   = (int*)alloc(1024);
  int*   ssort  = (int*)alloc((size_t)E * 4);

  const int NB = (N + 255) / 256;

  k_prep<<<128, 256, 0, stream>>>(W1, w1t, cnt, N);

  int nwave = (N + 15) / 16;
  k_gemm1<<<(nwave + 3) / 4, 256, 0, stream>>>(x, w1t, a1s, a1d, h1h, als, ald, N);

  k_hist<<<(E + 255) / 256, 256, 0, stream>>>(dstp, cnt, E);
  k_scan1<<<NB, 256, 0, stream>>>(cnt, offs, bsum, N);
  k_scan2<<<1, 256, 0, stream>>>(bsum, boff, NB);
  k_scan3<<<NB, 256, 0, stream>>>(offs, cursor, boff, bsum, N, NB);
  k_scatter<<<(E + 255) / 256, 256, 0, stream>>>(srcp, dstp, cursor, ssort, E);

  k_agg1<<<(N + 3) / 4, 256, 0, stream>>>(h1h, als, ald, offs, ssort, b1, W2,
                                          a2s, a2d, h2, al2s, al2d, N);
  k_agg2<<<(N * 8 + 255) / 256, 256, 0, stream>>>(h2, al2s, al2d, offs, ssort, b2, out, N);
}

// Round 6
// 238.867 us; speedup vs baseline: 2.4282x; 1.1640x over previous
//
#include <hip/hip_runtime.h>
#include <hip/hip_fp16.h>

#define LRELU(v) ((v) > 0.0f ? (v) : 0.2f * (v))

constexpr int F_IN = 128;
constexpr int NH1  = 6;
constexpr int D1   = 192;   // NH1 * 32

typedef _Float16 half8 __attribute__((ext_vector_type(8)));
typedef float floatx4 __attribute__((ext_vector_type(4)));

__device__ __forceinline__ void wave_lds_fence() {
  __builtin_amdgcn_wave_barrier();
  asm volatile("s_waitcnt lgkmcnt(0)" ::: "memory");
  __builtin_amdgcn_wave_barrier();
}

// ---------------- hist + prep: per-edge segment position via atomic return ----------------
// also: W1 -> fp16 transposed [192][128] (disjoint index range, no dependency)
__global__ __launch_bounds__(256) void k_hist(const float* __restrict__ W1,
                                              __half* __restrict__ w1t,
                                              const int* __restrict__ dst,
                                              int* __restrict__ cnt,
                                              int* __restrict__ pose, int E) {
  int tid = blockIdx.x * 256 + threadIdx.x;
  if (tid < F_IN * D1) {
    int k = tid / D1, n = tid - k * D1;   // coalesced read of W1[k][n]
    w1t[(size_t)n * F_IN + k] = __float2half(W1[tid]);
  }
  if (tid < E) {
    pose[tid] = atomicAdd(&cnt[dst[tid]], 1);
  }
}

// ---------------- GEMM1 via MFMA + fused attention-logit epilogue ----------------
__global__ __launch_bounds__(256) void k_gemm1(const float* __restrict__ x,
                                               const __half* __restrict__ w1t,
                                               const float* __restrict__ a1s,
                                               const float* __restrict__ a1d,
                                               __half* __restrict__ h1h,
                                               float* __restrict__ als,
                                               float* __restrict__ ald, int N) {
  int wv = blockIdx.x * 4 + (threadIdx.x >> 6);
  int m0 = wv * 16;
  if (m0 >= N) return;
  int lane = threadIdx.x & 63;
  int ln15 = lane & 15, q = lane >> 4;

  float avs[12], avd[12];
#pragma unroll
  for (int f = 0; f < 12; ++f) {
    int idx = (f >> 1) * 32 + (f & 1) * 16 + ln15;
    avs[f] = a1s[idx];
    avd[f] = a1d[idx];
  }

  floatx4 acc[12];
#pragma unroll
  for (int f = 0; f < 12; ++f) acc[f] = (floatx4){0.f, 0.f, 0.f, 0.f};

  int arowi = m0 + ln15;
  if (arowi >= N) arowi = N - 1;
  const float* arow = x + (size_t)arowi * F_IN + q * 8;
#pragma unroll
  for (int kc = 0; kc < F_IN; kc += 32) {
    float4 u0 = *(const float4*)(arow + kc);
    float4 u1 = *(const float4*)(arow + kc + 4);
    half8 a;
    a[0] = (_Float16)u0.x; a[1] = (_Float16)u0.y; a[2] = (_Float16)u0.z; a[3] = (_Float16)u0.w;
    a[4] = (_Float16)u1.x; a[5] = (_Float16)u1.y; a[6] = (_Float16)u1.z; a[7] = (_Float16)u1.w;
#pragma unroll
    for (int f = 0; f < 12; ++f) {
      half8 b = *(const half8*)(w1t + (size_t)(16 * f + ln15) * F_IN + kc + q * 8);
      acc[f] = __builtin_amdgcn_mfma_f32_16x16x32_f16(a, b, acc[f], 0, 0, 0);
    }
  }

#pragma unroll
  for (int f = 0; f < 12; ++f) {
#pragma unroll
    for (int r = 0; r < 4; ++r) {
      int n = m0 + q * 4 + r;
      if (n < N) h1h[(size_t)n * D1 + 16 * f + ln15] = __float2half(acc[f][r]);
    }
  }

#pragma unroll
  for (int r = 0; r < 4; ++r) {
    float ps[6] = {0.f, 0.f, 0.f, 0.f, 0.f, 0.f};
    float pd[6] = {0.f, 0.f, 0.f, 0.f, 0.f, 0.f};
#pragma unroll
    for (int f = 0; f < 12; ++f) {
      ps[f >> 1] = fmaf(acc[f][r], avs[f], ps[f >> 1]);
      pd[f >> 1] = fmaf(acc[f][r], avd[f], pd[f >> 1]);
    }
#pragma unroll
    for (int h = 0; h < 6; ++h) {
#pragma unroll
      for (int m = 8; m; m >>= 1) {
        ps[h] += __shfl_xor(ps[h], m);
        pd[h] += __shfl_xor(pd[h], m);
      }
    }
    float os = 0.f, od = 0.f;
#pragma unroll
    for (int h = 0; h < 6; ++h)
      if (ln15 == h) { os = ps[h]; od = pd[h]; }
    int n = m0 + q * 4 + r;
    if (ln15 < 6 && n < N) {
      als[(size_t)n * 6 + ln15] = os;
      ald[(size_t)n * 6 + ln15] = od;
    }
  }
}

// ---------------- scans ----------------
__global__ void k_scan1(const int* __restrict__ cnt, int* __restrict__ offs,
                        int* __restrict__ bsum, int N) {
  int t = threadIdx.x;
  int idx = blockIdx.x * 256 + t;
  int lane = t & 63, w = t >> 6;
  int v = (idx < N) ? cnt[idx] : 0;
  int incl = v;
#pragma unroll
  for (int d = 1; d < 64; d <<= 1) {
    int u = __shfl_up(incl, d);
    if (lane >= d) incl += u;
  }
  __shared__ int wt[4];
  if (lane == 63) wt[w] = incl;
  __syncthreads();
  int woff = 0;
  for (int i = 0; i < w; ++i) woff += wt[i];
  if (idx < N) offs[idx] = woff + incl - v;
  if (t == 255) bsum[blockIdx.x] = woff + incl;
}

__global__ void k_scan2(int* __restrict__ bsum, int* __restrict__ boff, int NB) {
  int t = threadIdx.x;
  int lane = t & 63, w = t >> 6;
  int v = (t < NB) ? bsum[t] : 0;
  int incl = v;
#pragma unroll
  for (int d = 1; d < 64; d <<= 1) {
    int u = __shfl_up(incl, d);
    if (lane >= d) incl += u;
  }
  __shared__ int wt[4];
  if (lane == 63) wt[w] = incl;
  __syncthreads();
  int woff = 0;
  for (int i = 0; i < w; ++i) woff += wt[i];
  if (t < NB) boff[t] = woff + incl - v;
}

__global__ void k_scan3(int* __restrict__ offs, const int* __restrict__ boff,
                        const int* __restrict__ bsum, int N, int NB) {
  int idx = blockIdx.x * 256 + threadIdx.x;
  if (idx < N) offs[idx] += boff[blockIdx.x];
  if (idx == 0) offs[N] = boff[NB - 1] + bsum[NB - 1];
}

// ---------------- place: atomic-free scatter using saved positions ----------------
__global__ __launch_bounds__(256) void k_place(const int* __restrict__ src,
                                               const int* __restrict__ dst,
                                               const int* __restrict__ offs,
                                               const int* __restrict__ pose,
                                               int* __restrict__ ssort, int E) {
  int e = blockIdx.x * 256 + threadIdx.x;
  if (e < E) {
    ssort[offs[dst[e]] + pose[e]] = src[e];
  }
}

// ---------------- layer-1 aggregation + fused layer-2 node transform ----------------
__global__ __launch_bounds__(256) void k_agg1(
    const __half* __restrict__ h1h, const float* __restrict__ als, const float* __restrict__ ald,
    const int* __restrict__ offs, const int* __restrict__ srcs,
    const float* __restrict__ b1, const float* __restrict__ W2,
    const float* __restrict__ a2s, const float* __restrict__ a2d,
    float* __restrict__ h2, float* __restrict__ al2s, float* __restrict__ al2d, int N) {
  __shared__ float wbuf[4][64][9];
  int wid = threadIdx.x >> 6, lane = threadIdx.x & 63;
  int d = blockIdx.x * 4 + wid;
  if (d >= N) return;
  int off = offs[d], cnt = offs[d + 1] - off;
  int tot = cnt + 1;

  float aldh[6];
  {
    const float* ap = ald + (size_t)d * 6;
    float2 q0 = *(const float2*)ap, q1 = *(const float2*)(ap + 2), q2 = *(const float2*)(ap + 4);
    aldh[0] = q0.x; aldh[1] = q0.y; aldh[2] = q1.x;
    aldh[3] = q1.y; aldh[4] = q2.x; aldh[5] = q2.y;
  }

  float dh[6] = {0.f, 0.f, 0.f, 0.f, 0.f, 0.f};
  int nchunk = (tot + 63) >> 6;

  float a0 = 0.f, a1 = 0.f, a2 = 0.f;
  const int hw = lane >> 4;
  const int hh = 4 + (lane >> 5);

  auto body = [&](int j) {
    float w_a = wbuf[wid][j][hw];
    float w_b = wbuf[wid][j][hh];
    int s = __float_as_int(wbuf[wid][j][6]);
    const __half* hp = h1h + (size_t)s * D1;
    float2 v = __half22float2(*(const __half2*)(hp + 2 * lane));
    float vh = __half2float(hp[128 + lane]);
    a0 = fmaf(w_a, v.x, a0);
    a1 = fmaf(w_a, v.y, a1);
    a2 = fmaf(w_b, vh, a2);
  };
  auto jloop = [&](int jmax) {
    int j = 0;
    for (; j + 3 < jmax; j += 4) { body(j); body(j + 1); body(j + 2); body(j + 3); }
    for (; j < jmax; ++j) body(j);
  };

  if (nchunk == 1) {
    float wreg[6];
    int sreg = 0;
    if (lane < tot) {
      int s = (lane == cnt) ? d : srcs[off + lane];
      sreg = s;
      const float* ap = als + (size_t)s * 6;
      float2 p0 = *(const float2*)ap, p1 = *(const float2*)(ap + 2), p2 = *(const float2*)(ap + 4);
      float ev[6] = {p0.x, p0.y, p1.x, p1.y, p2.x, p2.y};
#pragma unroll
      for (int h = 0; h < 6; ++h) {
        float e = ev[h] + aldh[h];
        e = LRELU(e);
        wreg[h] = __expf(e);
        dh[h] = wreg[h];
      }
    }
#pragma unroll
    for (int h = 0; h < 6; ++h) {
#pragma unroll
      for (int m = 32; m; m >>= 1) dh[h] += __shfl_xor(dh[h], m);
      dh[h] = 1.0f / dh[h];
    }
    if (lane < tot) {
#pragma unroll
      for (int h = 0; h < 6; ++h) wbuf[wid][lane][h] = wreg[h] * dh[h];
      wbuf[wid][lane][6] = __int_as_float(sreg);
    }
    wave_lds_fence();
    jloop(tot);
  } else {
    for (int c = 0; c < nchunk; ++c) {
      int i = c * 64 + lane;
      if (i < tot) {
        int s = (i == cnt) ? d : srcs[off + i];
        const float* ap = als + (size_t)s * 6;
        float2 p0 = *(const float2*)ap, p1 = *(const float2*)(ap + 2), p2 = *(const float2*)(ap + 4);
        float ev[6] = {p0.x, p0.y, p1.x, p1.y, p2.x, p2.y};
#pragma unroll
        for (int h = 0; h < 6; ++h) {
          float e = ev[h] + aldh[h];
          e = LRELU(e);
          dh[h] += __expf(e);
        }
      }
    }
#pragma unroll
    for (int h = 0; h < 6; ++h) {
#pragma unroll
      for (int m = 32; m; m >>= 1) dh[h] += __shfl_xor(dh[h], m);
      dh[h] = 1.0f / dh[h];
    }
    for (int c = 0; c < nchunk; ++c) {
      int i = c * 64 + lane;
      if (i < tot) {
        int s = (i == cnt) ? d : srcs[off + i];
        const float* ap = als + (size_t)s * 6;
        float2 p0 = *(const float2*)ap, p1 = *(const float2*)(ap + 2), p2 = *(const float2*)(ap + 4);
        float ev[6] = {p0.x, p0.y, p1.x, p1.y, p2.x, p2.y};
#pragma unroll
        for (int h = 0; h < 6; ++h) {
          float e = ev[h] + aldh[h];
          e = LRELU(e);
          wbuf[wid][lane][h] = __expf(e) * dh[h];
        }
        wbuf[wid][lane][6] = __int_as_float(s);
      }
      wave_lds_fence();
      int jmax = tot - c * 64;
      if (jmax > 64) jmax = 64;
      jloop(jmax);
      wave_lds_fence();
    }
  }

  float2 bv = *(const float2*)(b1 + 2 * lane);
  float v0 = fmaxf(a0 + bv.x, 0.f);
  float v1 = fmaxf(a1 + bv.y, 0.f);
  float v2 = fmaxf(a2 + b1[128 + lane], 0.f);
  float4 ww = *(const float4*)(W2 + 4 * lane);
  float2 wh = *(const float2*)(W2 + (128 + lane) * 2);
  float s0 = v0 * ww.x + v1 * ww.z + v2 * wh.x;
  float s1 = v0 * ww.y + v1 * ww.w + v2 * wh.y;
#pragma unroll
  for (int m = 32; m; m >>= 1) {
    s0 += __shfl_xor(s0, m);
    s1 += __shfl_xor(s1, m);
  }
  if (lane == 0) {
    h2[d * 2] = s0;
    h2[d * 2 + 1] = s1;
    al2s[d] = s0 * a2s[0] + s1 * a2s[1];
    al2d[d] = s0 * a2d[0] + s1 * a2d[1];
  }
}

// ---------------- layer-2 aggregation + bias + log_softmax ----------------
__global__ __launch_bounds__(256) void k_agg2(
    const float* __restrict__ h2, const float* __restrict__ al2s,
    const float* __restrict__ al2d, const int* __restrict__ offs,
    const int* __restrict__ srcs, const float* __restrict__ b2,
    float* __restrict__ out, int N) {
  int tid = blockIdx.x * 256 + threadIdx.x;
  int g = tid >> 3, r = tid & 7;
  if (g >= N) return;
  int off = offs[g], cnt = offs[g + 1] - off;
  int tot = cnt + 1;
  float ad = al2d[g];
  float den = 0.f, o0 = 0.f, o1 = 0.f;
  for (int i = r; i < tot; i += 8) {
    int s = (i == cnt) ? g : srcs[off + i];
    float e = al2s[s] + ad;
    e = LRELU(e);
    float a = __expf(e);
    float2 hv = *(const float2*)(h2 + (size_t)s * 2);
    den += a;
    o0 = fmaf(a, hv.x, o0);
    o1 = fmaf(a, hv.y, o1);
  }
#pragma unroll
  for (int m = 4; m; m >>= 1) {
    den += __shfl_xor(den, m);
    o0 += __shfl_xor(o0, m);
    o1 += __shfl_xor(o1, m);
  }
  if (r == 0) {
    float inv = 1.0f / den;
    o0 = o0 * inv + b2[0];
    o1 = o1 * inv + b2[1];
    float mm = fmaxf(o0, o1);
    float l = mm + logf(__expf(o0 - mm) + __expf(o1 - mm));
    *(float2*)(out + (size_t)g * 2) = make_float2(o0 - l, o1 - l);
  }
}

extern "C" void kernel_launch(void* const* d_in, const int* in_sizes, int n_in,
                              void* d_out, int out_size, void* d_ws, size_t ws_size,
                              hipStream_t stream) {
  const float* x   = (const float*)d_in[0];
  const int*   ei  = (const int*)d_in[1];
  const float* W1  = (const float*)d_in[2];
  const float* a1s = (const float*)d_in[3];
  const float* a1d = (const float*)d_in[4];
  const float* b1  = (const float*)d_in[5];
  const float* W2  = (const float*)d_in[6];
  const float* a2s = (const float*)d_in[7];
  const float* a2d = (const float*)d_in[8];
  const float* b2  = (const float*)d_in[9];
  float* out = (float*)d_out;

  const int N = in_sizes[0] / F_IN;   // 50000
  const int E = in_sizes[1] / 2;      // 800000
  const int* srcp = ei;
  const int* dstp = ei + E;

  char* w = (char*)d_ws;
  auto alloc = [&](size_t bytes) {
    char* p = w;
    w += (bytes + 255) & ~(size_t)255;
    return p;
  };
  __half* h1h   = (__half*)alloc((size_t)N * D1 * 2);
  __half* w1t   = (__half*)alloc((size_t)F_IN * D1 * 2);
  float* als    = (float*)alloc((size_t)N * NH1 * 4);
  float* ald    = (float*)alloc((size_t)N * NH1 * 4);
  float* h2     = (float*)alloc((size_t)N * 2 * 4);
  float* al2s   = (float*)alloc((size_t)N * 4);
  float* al2d   = (float*)alloc((size_t)N * 4);
  int*   cnt    = (int*)alloc((size_t)N * 4);
  int*   offs   = (int*)alloc((size_t)(N + 1) * 4);
  int*   pose   = (int*)alloc((size_t)E * 4);
  int*   bsum   = (int*)alloc(1024);
  int*   boff   = (int*)alloc(1024);
  int*   ssort  = (int*)alloc((size_t)E * 4);

  const int NB = (N + 255) / 256;

  hipMemsetAsync(cnt, 0, (size_t)N * 4, stream);

  k_hist<<<(E + 255) / 256, 256, 0, stream>>>(W1, w1t, dstp, cnt, pose, E);

  int nwave = (N + 15) / 16;
  k_gemm1<<<(nwave + 3) / 4, 256, 0, stream>>>(x, w1t, a1s, a1d, h1h, als, ald, N);

  k_scan1<<<NB, 256, 0, stream>>>(cnt, offs, bsum, N);
  k_scan2<<<1, 256, 0, stream>>>(bsum, boff, NB);
  k_scan3<<<NB, 256, 0, stream>>>(offs, boff, bsum, N, NB);
  k_place<<<(E + 255) / 256, 256, 0, stream>>>(srcp, dstp, offs, pose, ssort, E);

  k_agg1<<<(N + 3) / 4, 256, 0, stream>>>(h1h, als, ald, offs, ssort, b1, W2,
                                          a2s, a2d, h2, al2s, al2d, N);
  k_agg2<<<(N * 8 + 255) / 256, 256, 0, stream>>>(h2, al2s, al2d, offs, ssort, b2, out, N);
}

// Round 7
// 237.653 us; speedup vs baseline: 2.4406x; 1.0051x over previous
//
#include <hip/hip_runtime.h>
#include <hip/hip_fp16.h>

#define LRELU(v) ((v) > 0.0f ? (v) : 0.2f * (v))

constexpr int F_IN = 128;
constexpr int NH1  = 6;
constexpr int D1   = 192;   // NH1 * 32

typedef _Float16 half8 __attribute__((ext_vector_type(8)));
typedef float floatx4 __attribute__((ext_vector_type(4)));

__device__ __forceinline__ void wave_lds_fence() {
  __builtin_amdgcn_wave_barrier();
  asm volatile("s_waitcnt lgkmcnt(0)" ::: "memory");
  __builtin_amdgcn_wave_barrier();
}

// ---------------- hist (8-way sharded) + W1 prep ----------------
// shard = blockIdx&7 (== (e>>8)&7 for 256-thread blocks): heuristic XCD affinity
// so each counter line is mostly hit from one XCD -> local-L2 atomic latency.
__global__ __launch_bounds__(256) void k_hist(const float* __restrict__ W1,
                                              __half* __restrict__ w1t,
                                              const int* __restrict__ dst,
                                              int* __restrict__ cnt,      // [8][N]
                                              int* __restrict__ pose, int N, int E) {
  int tid = blockIdx.x * 256 + threadIdx.x;
  if (tid < F_IN * D1) {
    int k = tid / D1, n = tid - k * D1;   // coalesced read of W1[k][n]
    w1t[(size_t)n * F_IN + k] = __float2half(W1[tid]);
  }
  if (tid < E) {
    int s = blockIdx.x & 7;
    pose[tid] = atomicAdd(&cnt[s * N + dst[tid]], 1);
  }
}

// ---------------- GEMM1 via MFMA + fused attention-logit epilogue ----------------
__global__ __launch_bounds__(256) void k_gemm1(const float* __restrict__ x,
                                               const __half* __restrict__ w1t,
                                               const float* __restrict__ a1s,
                                               const float* __restrict__ a1d,
                                               __half* __restrict__ h1h,
                                               float* __restrict__ als,
                                               float* __restrict__ ald, int N) {
  int wv = blockIdx.x * 4 + (threadIdx.x >> 6);
  int m0 = wv * 16;
  if (m0 >= N) return;
  int lane = threadIdx.x & 63;
  int ln15 = lane & 15, q = lane >> 4;

  float avs[12], avd[12];
#pragma unroll
  for (int f = 0; f < 12; ++f) {
    int idx = (f >> 1) * 32 + (f & 1) * 16 + ln15;
    avs[f] = a1s[idx];
    avd[f] = a1d[idx];
  }

  floatx4 acc[12];
#pragma unroll
  for (int f = 0; f < 12; ++f) acc[f] = (floatx4){0.f, 0.f, 0.f, 0.f};

  int arowi = m0 + ln15;
  if (arowi >= N) arowi = N - 1;
  const float* arow = x + (size_t)arowi * F_IN + q * 8;
#pragma unroll
  for (int kc = 0; kc < F_IN; kc += 32) {
    float4 u0 = *(const float4*)(arow + kc);
    float4 u1 = *(const float4*)(arow + kc + 4);
    half8 a;
    a[0] = (_Float16)u0.x; a[1] = (_Float16)u0.y; a[2] = (_Float16)u0.z; a[3] = (_Float16)u0.w;
    a[4] = (_Float16)u1.x; a[5] = (_Float16)u1.y; a[6] = (_Float16)u1.z; a[7] = (_Float16)u1.w;
#pragma unroll
    for (int f = 0; f < 12; ++f) {
      half8 b = *(const half8*)(w1t + (size_t)(16 * f + ln15) * F_IN + kc + q * 8);
      acc[f] = __builtin_amdgcn_mfma_f32_16x16x32_f16(a, b, acc[f], 0, 0, 0);
    }
  }

#pragma unroll
  for (int f = 0; f < 12; ++f) {
#pragma unroll
    for (int r = 0; r < 4; ++r) {
      int n = m0 + q * 4 + r;
      if (n < N) h1h[(size_t)n * D1 + 16 * f + ln15] = __float2half(acc[f][r]);
    }
  }

#pragma unroll
  for (int r = 0; r < 4; ++r) {
    float ps[6] = {0.f, 0.f, 0.f, 0.f, 0.f, 0.f};
    float pd[6] = {0.f, 0.f, 0.f, 0.f, 0.f, 0.f};
#pragma unroll
    for (int f = 0; f < 12; ++f) {
      ps[f >> 1] = fmaf(acc[f][r], avs[f], ps[f >> 1]);
      pd[f >> 1] = fmaf(acc[f][r], avd[f], pd[f >> 1]);
    }
#pragma unroll
    for (int h = 0; h < 6; ++h) {
#pragma unroll
      for (int m = 8; m; m >>= 1) {
        ps[h] += __shfl_xor(ps[h], m);
        pd[h] += __shfl_xor(pd[h], m);
      }
    }
    float os = 0.f, od = 0.f;
#pragma unroll
    for (int h = 0; h < 6; ++h)
      if (ln15 == h) { os = ps[h]; od = pd[h]; }
    int n = m0 + q * 4 + r;
    if (ln15 < 6 && n < N) {
      als[(size_t)n * 6 + ln15] = os;
      ald[(size_t)n * 6 + ln15] = od;
    }
  }
}

// ---------------- scanA: shard-fold + per-block exclusive scan ----------------
__global__ void k_scanA(const int* __restrict__ cnt, int* __restrict__ spre,
                        int* __restrict__ offs, int* __restrict__ bsum, int N) {
  int t = threadIdx.x;
  int idx = blockIdx.x * 256 + t;
  int lane = t & 63, w = t >> 6;
  int run = 0;
#pragma unroll
  for (int s = 0; s < 8; ++s) {
    int c = (idx < N) ? cnt[s * N + idx] : 0;
    if (idx < N) spre[s * N + idx] = run;
    run += c;
  }
  int v = run;  // node total
  int incl = v;
#pragma unroll
  for (int d = 1; d < 64; d <<= 1) {
    int u = __shfl_up(incl, d);
    if (lane >= d) incl += u;
  }
  __shared__ int wt[4];
  if (lane == 63) wt[w] = incl;
  __syncthreads();
  int woff = 0;
  for (int i = 0; i < w; ++i) woff += wt[i];
  if (idx < N) offs[idx] = woff + incl - v;
  if (t == 255) bsum[blockIdx.x] = woff + incl;
}

__global__ void k_scanB(int* __restrict__ bsum, int* __restrict__ boff, int NB) {
  int t = threadIdx.x;
  int lane = t & 63, w = t >> 6;
  int v = (t < NB) ? bsum[t] : 0;
  int incl = v;
#pragma unroll
  for (int d = 1; d < 64; d <<= 1) {
    int u = __shfl_up(incl, d);
    if (lane >= d) incl += u;
  }
  __shared__ int wt[4];
  if (lane == 63) wt[w] = incl;
  __syncthreads();
  int woff = 0;
  for (int i = 0; i < w; ++i) woff += wt[i];
  if (t < NB) boff[t] = woff + incl - v;
}

__global__ void k_scanC(int* __restrict__ offs, const int* __restrict__ boff,
                        const int* __restrict__ bsum, int N, int NB) {
  int idx = blockIdx.x * 256 + threadIdx.x;
  if (idx < N) offs[idx] += boff[blockIdx.x];
  if (idx == 0) offs[N] = boff[NB - 1] + bsum[NB - 1];
}

// ---------------- place: atomic-free scatter ----------------
__global__ __launch_bounds__(256) void k_place(const int* __restrict__ src,
                                               const int* __restrict__ dst,
                                               const int* __restrict__ offs,
                                               const int* __restrict__ spre,
                                               const int* __restrict__ pose,
                                               int* __restrict__ ssort, int N, int E) {
  int e = blockIdx.x * 256 + threadIdx.x;
  if (e < E) {
    int d = dst[e];
    int s = (e >> 8) & 7;
    ssort[offs[d] + spre[s * N + d] + pose[e]] = src[e];
  }
}

// ---------------- layer-1 aggregation + fused layer-2 node transform ----------------
__global__ __launch_bounds__(256) void k_agg1(
    const __half* __restrict__ h1h, const float* __restrict__ als, const float* __restrict__ ald,
    const int* __restrict__ offs, const int* __restrict__ srcs,
    const float* __restrict__ b1, const float* __restrict__ W2,
    const float* __restrict__ a2s, const float* __restrict__ a2d,
    float4* __restrict__ pk, int N) {   // pk[d] = {h2x, h2y, al2s, al2d}
  __shared__ float wbuf[4][64][9];
  int wid = threadIdx.x >> 6, lane = threadIdx.x & 63;
  int d = blockIdx.x * 4 + wid;
  if (d >= N) return;
  int off = offs[d], cnt = offs[d + 1] - off;
  int tot = cnt + 1;

  float aldh[6];
  {
    const float* ap = ald + (size_t)d * 6;
    float2 q0 = *(const float2*)ap, q1 = *(const float2*)(ap + 2), q2 = *(const float2*)(ap + 4);
    aldh[0] = q0.x; aldh[1] = q0.y; aldh[2] = q1.x;
    aldh[3] = q1.y; aldh[4] = q2.x; aldh[5] = q2.y;
  }

  float dh[6] = {0.f, 0.f, 0.f, 0.f, 0.f, 0.f};
  int nchunk = (tot + 63) >> 6;

  float a0 = 0.f, a1 = 0.f, a2 = 0.f;
  const int hw = lane >> 4;
  const int hh = 4 + (lane >> 5);

  auto body = [&](int j) {
    float w_a = wbuf[wid][j][hw];
    float w_b = wbuf[wid][j][hh];
    int soff = __float_as_int(wbuf[wid][j][6]);   // byte offset = s * 384
    const __half* hp = (const __half*)((const char*)h1h + soff);
    float2 v = __half22float2(*(const __half2*)(hp + 2 * lane));
    float vh = __half2float(hp[128 + lane]);
    a0 = fmaf(w_a, v.x, a0);
    a1 = fmaf(w_a, v.y, a1);
    a2 = fmaf(w_b, vh, a2);
  };
  auto jloop = [&](int jmax) {
    int j = 0;
    for (; j + 3 < jmax; j += 4) { body(j); body(j + 1); body(j + 2); body(j + 3); }
    for (; j < jmax; ++j) body(j);
  };

  if (nchunk == 1) {
    float wreg[6];
    int sreg = 0;
    if (lane < tot) {
      int s = (lane == cnt) ? d : srcs[off + lane];
      sreg = s;
      const float* ap = als + (size_t)s * 6;
      float2 p0 = *(const float2*)ap, p1 = *(const float2*)(ap + 2), p2 = *(const float2*)(ap + 4);
      float ev[6] = {p0.x, p0.y, p1.x, p1.y, p2.x, p2.y};
#pragma unroll
      for (int h = 0; h < 6; ++h) {
        float e = ev[h] + aldh[h];
        e = LRELU(e);
        wreg[h] = __expf(e);
        dh[h] = wreg[h];
      }
    }
#pragma unroll
    for (int h = 0; h < 6; ++h) {
#pragma unroll
      for (int m = 32; m; m >>= 1) dh[h] += __shfl_xor(dh[h], m);
      dh[h] = 1.0f / dh[h];
    }
    if (lane < tot) {
#pragma unroll
      for (int h = 0; h < 6; ++h) wbuf[wid][lane][h] = wreg[h] * dh[h];
      wbuf[wid][lane][6] = __int_as_float(sreg * (D1 * 2));
    }
    wave_lds_fence();
    jloop(tot);
  } else {
    for (int c = 0; c < nchunk; ++c) {
      int i = c * 64 + lane;
      if (i < tot) {
        int s = (i == cnt) ? d : srcs[off + i];
        const float* ap = als + (size_t)s * 6;
        float2 p0 = *(const float2*)ap, p1 = *(const float2*)(ap + 2), p2 = *(const float2*)(ap + 4);
        float ev[6] = {p0.x, p0.y, p1.x, p1.y, p2.x, p2.y};
#pragma unroll
        for (int h = 0; h < 6; ++h) {
          float e = ev[h] + aldh[h];
          e = LRELU(e);
          dh[h] += __expf(e);
        }
      }
    }
#pragma unroll
    for (int h = 0; h < 6; ++h) {
#pragma unroll
      for (int m = 32; m; m >>= 1) dh[h] += __shfl_xor(dh[h], m);
      dh[h] = 1.0f / dh[h];
    }
    for (int c = 0; c < nchunk; ++c) {
      int i = c * 64 + lane;
      if (i < tot) {
        int s = (i == cnt) ? d : srcs[off + i];
        const float* ap = als + (size_t)s * 6;
        float2 p0 = *(const float2*)ap, p1 = *(const float2*)(ap + 2), p2 = *(const float2*)(ap + 4);
        float ev[6] = {p0.x, p0.y, p1.x, p1.y, p2.x, p2.y};
#pragma unroll
        for (int h = 0; h < 6; ++h) {
          float e = ev[h] + aldh[h];
          e = LRELU(e);
          wbuf[wid][lane][h] = __expf(e) * dh[h];
        }
        wbuf[wid][lane][6] = __int_as_float(s * (D1 * 2));
      }
      wave_lds_fence();
      int jmax = tot - c * 64;
      if (jmax > 64) jmax = 64;
      jloop(jmax);
      wave_lds_fence();
    }
  }

  float2 bv = *(const float2*)(b1 + 2 * lane);
  float v0 = fmaxf(a0 + bv.x, 0.f);
  float v1 = fmaxf(a1 + bv.y, 0.f);
  float v2 = fmaxf(a2 + b1[128 + lane], 0.f);
  float4 ww = *(const float4*)(W2 + 4 * lane);
  float2 wh = *(const float2*)(W2 + (128 + lane) * 2);
  float s0 = v0 * ww.x + v1 * ww.z + v2 * wh.x;
  float s1 = v0 * ww.y + v1 * ww.w + v2 * wh.y;
#pragma unroll
  for (int m = 32; m; m >>= 1) {
    s0 += __shfl_xor(s0, m);
    s1 += __shfl_xor(s1, m);
  }
  if (lane == 0) {
    pk[d] = make_float4(s0, s1,
                        s0 * a2s[0] + s1 * a2s[1],
                        s0 * a2d[0] + s1 * a2d[1]);
  }
}

// ---------------- layer-2 aggregation + bias + log_softmax ----------------
__global__ __launch_bounds__(256) void k_agg2(
    const float4* __restrict__ pk, const int* __restrict__ offs,
    const int* __restrict__ srcs, const float* __restrict__ b2,
    float* __restrict__ out, int N) {
  int tid = blockIdx.x * 256 + threadIdx.x;
  int g = tid >> 3, r = tid & 7;
  if (g >= N) return;
  int off = offs[g], cnt = offs[g + 1] - off;
  int tot = cnt + 1;
  float ad = pk[g].w;
  float den = 0.f, o0 = 0.f, o1 = 0.f;
  for (int i = r; i < tot; i += 8) {
    int s = (i == cnt) ? g : srcs[off + i];
    float4 p = pk[s];
    float e = p.z + ad;
    e = LRELU(e);
    float a = __expf(e);
    den += a;
    o0 = fmaf(a, p.x, o0);
    o1 = fmaf(a, p.y, o1);
  }
#pragma unroll
  for (int m = 4; m; m >>= 1) {
    den += __shfl_xor(den, m);
    o0 += __shfl_xor(o0, m);
    o1 += __shfl_xor(o1, m);
  }
  if (r == 0) {
    float inv = 1.0f / den;
    o0 = o0 * inv + b2[0];
    o1 = o1 * inv + b2[1];
    float mm = fmaxf(o0, o1);
    float l = mm + logf(__expf(o0 - mm) + __expf(o1 - mm));
    *(float2*)(out + (size_t)g * 2) = make_float2(o0 - l, o1 - l);
  }
}

extern "C" void kernel_launch(void* const* d_in, const int* in_sizes, int n_in,
                              void* d_out, int out_size, void* d_ws, size_t ws_size,
                              hipStream_t stream) {
  const float* x   = (const float*)d_in[0];
  const int*   ei  = (const int*)d_in[1];
  const float* W1  = (const float*)d_in[2];
  const float* a1s = (const float*)d_in[3];
  const float* a1d = (const float*)d_in[4];
  const float* b1  = (const float*)d_in[5];
  const float* W2  = (const float*)d_in[6];
  const float* a2s = (const float*)d_in[7];
  const float* a2d = (const float*)d_in[8];
  const float* b2  = (const float*)d_in[9];
  float* out = (float*)d_out;

  const int N = in_sizes[0] / F_IN;   // 50000
  const int E = in_sizes[1] / 2;      // 800000
  const int* srcp = ei;
  const int* dstp = ei + E;

  char* w = (char*)d_ws;
  auto alloc = [&](size_t bytes) {
    char* p = w;
    w += (bytes + 255) & ~(size_t)255;
    return p;
  };
  __half* h1h   = (__half*)alloc((size_t)N * D1 * 2);
  __half* w1t   = (__half*)alloc((size_t)F_IN * D1 * 2);
  float* als    = (float*)alloc((size_t)N * NH1 * 4);
  float* ald    = (float*)alloc((size_t)N * NH1 * 4);
  float4* pk    = (float4*)alloc((size_t)N * 16);
  int*   cnt    = (int*)alloc((size_t)N * 8 * 4);   // [8][N]
  int*   spre   = (int*)alloc((size_t)N * 8 * 4);   // [8][N]
  int*   offs   = (int*)alloc((size_t)(N + 1) * 4);
  int*   pose   = (int*)alloc((size_t)E * 4);
  int*   bsum   = (int*)alloc(1024);
  int*   boff   = (int*)alloc(1024);
  int*   ssort  = (int*)alloc((size_t)E * 4);

  const int NB = (N + 255) / 256;

  hipMemsetAsync(cnt, 0, (size_t)N * 8 * 4, stream);

  k_hist<<<(E + 255) / 256, 256, 0, stream>>>(W1, w1t, dstp, cnt, pose, N, E);

  int nwave = (N + 15) / 16;
  k_gemm1<<<(nwave + 3) / 4, 256, 0, stream>>>(x, w1t, a1s, a1d, h1h, als, ald, N);

  k_scanA<<<NB, 256, 0, stream>>>(cnt, spre, offs, bsum, N);
  k_scanB<<<1, 256, 0, stream>>>(bsum, boff, NB);
  k_scanC<<<NB, 256, 0, stream>>>(offs, boff, bsum, N, NB);
  k_place<<<(E + 255) / 256, 256, 0, stream>>>(srcp, dstp, offs, spre, pose, ssort, N, E);

  k_agg1<<<(N + 3) / 4, 256, 0, stream>>>(h1h, als, ald, offs, ssort, b1, W2,
                                          a2s, a2d, pk, N);
  k_agg2<<<(N * 8 + 255) / 256, 256, 0, stream>>>(pk, offs, ssort, b2, out, N);
}